// Round 10
// baseline (242.888 us; speedup 1.0000x reference)
//
#include <hip/hip_runtime.h>
#include <hip/hip_bf16.h>
#include <cmath>

// B=8, T=1024, C=768, H=12, D=64
#define B_ 8
#define T_ 1024
#define C_ 768
#define H_ 12
#define D_ 64
#define N3C 2304
#define M_ 8192   // B*T

typedef __bf16 bf16x4 __attribute__((ext_vector_type(4)));
typedef __bf16 bf16x8 __attribute__((ext_vector_type(8)));
typedef float  f32x4  __attribute__((ext_vector_type(4)));

typedef const __attribute__((address_space(1))) void* gptr_t;
typedef __attribute__((address_space(3))) void* lptr_t;

#define LOG2E 1.44269504088896f

__device__ __forceinline__ bf16x8 cvt_bf16x8(const float4& a, const float4& b) {
    bf16x8 r;
    r[0] = (__bf16)a.x; r[1] = (__bf16)a.y; r[2] = (__bf16)a.z; r[3] = (__bf16)a.w;
    r[4] = (__bf16)b.x; r[5] = (__bf16)b.y; r[6] = (__bf16)b.z; r[7] = (__bf16)b.w;
    return r;
}

// ---------------- fused pre-pass: cast x + transpose-cast both weights ----------------
__global__ __launch_bounds__(256) void prepass(const float* __restrict__ x,
                                               __bf16* __restrict__ xb,
                                               const float* __restrict__ wa,
                                               __bf16* __restrict__ wat,
                                               const float* __restrict__ wp,
                                               __bf16* __restrict__ wpt) {
    __shared__ float tile[32][33];
    const int bx = blockIdx.x, tid = threadIdx.x;
    if (bx < 3072) {
        int i = (bx * 256 + tid) * 8;
        float4 a = *(const float4*)&x[i];
        float4 b = *(const float4*)&x[i + 4];
        *(bf16x8*)&xb[i] = cvt_bf16x8(a, b);
        return;
    }
    const float* w;
    __bf16* wt;
    int K, N, n0, k0;
    if (bx < 4800) {
        int bb = bx - 3072;           // w_attn: 72 n-tiles x 24 k-tiles
        w = wa; wt = wat; K = 768; N = 2304;
        n0 = (bb % 72) * 32; k0 = (bb / 72) * 32;
    } else {
        int bb = bx - 4800;           // w_proj: 24 x 24 tiles
        w = wp; wt = wpt; K = 768; N = 768;
        n0 = (bb % 24) * 32; k0 = (bb / 24) * 32;
    }
    int tx = tid & 31, ty = tid >> 5;
#pragma unroll
    for (int i = 0; i < 4; i++)
        tile[ty + i * 8][tx] = w[(size_t)(k0 + ty + i * 8) * N + n0 + tx];
    __syncthreads();
#pragma unroll
    for (int i = 0; i < 4; i++)
        wt[(size_t)(n0 + ty + i * 8) * K + k0 + tx] = (__bf16)tile[tx][ty + i * 8];
}

// ---------------- QKV GEMM v6 (best measured 43.5-45.5us fast-mode): 256x128, BK=64, 8 waves, 4-phase + counted vmcnt ----------------
// Triple-buffered LDS (144KB); tile kc+2's 6 loads issued split across tile kc's 4
// phases; boundary vmcnt(6) (never 0 in main loop). Phase = {ds_read frags || issue
// prefetch -> barrier -> setprio(1) -> 8 MFMA -> setprio(0)}.
// DO NOT coarsen the phases (round 3: -7%) and DO NOT dbuf-within-2-blocks (round 1: flat).
__global__ __launch_bounds__(512, 2) void qkv_gemm_mfma(const __bf16* __restrict__ A,
                                                        const __bf16* __restrict__ Bt,
                                                        const float* __restrict__ bias,
                                                        __bf16* __restrict__ qb,
                                                        __bf16* __restrict__ kb,
                                                        __bf16* __restrict__ vbt) {
    __shared__ __bf16 smem[73728];               // 144KB: A 3x16384 | B 3x8192; epilogue reuses
    __bf16* Abuf = smem;
    __bf16* Bbuf = smem + 49152;
    const int tid = threadIdx.x;
    const int wave = tid >> 6, lane = tid & 63;
    const int lane15 = lane & 15, quad = lane >> 4;
    // XCD-chunked swizzle: 576 blocks, 72 per XCD, n-major within chunk (B panel L2-resident)
    const int swz = (blockIdx.x & 7) * 72 + (blockIdx.x >> 3);
    const int n0 = (swz % 18) * 128;
    const int m0 = (swz / 18) * 256;
    const int wm = (wave >> 1) * 64, wn = (wave & 1) * 64;
    f32x4 acc[4][4] = {};

#define ISSUE_A2(KC, R0)                                                            \
    {                                                                               \
        const int k0s = (KC) * 64;                                                  \
        __bf16* Ad = Abuf + ((KC) % 3) * 16384;                                     \
        _Pragma("unroll")                                                           \
        for (int r = (R0); r < (R0) + 2; ++r) {                                     \
            int p = r * 512 + tid;                                                  \
            int row = p >> 3, csw = p & 7;                                          \
            __builtin_amdgcn_global_load_lds(                                       \
                (gptr_t)(A + (size_t)(m0 + row) * 768 + k0s + (csw ^ (row & 7)) * 8), \
                (lptr_t)(Ad + (r * 512 + wave * 64) * 8), 16, 0, 0);                \
        }                                                                           \
    }

#define ISSUE_B1(KC, R0)                                                            \
    {                                                                               \
        const int k0s = (KC) * 64;                                                  \
        __bf16* Bd = Bbuf + ((KC) % 3) * 8192;                                      \
        int p = (R0) * 512 + tid;                                                   \
        int row = p >> 3, csw = p & 7;                                              \
        __builtin_amdgcn_global_load_lds(                                           \
            (gptr_t)(Bt + (size_t)(n0 + row) * 768 + k0s + (csw ^ (row & 7)) * 8),  \
            (lptr_t)(Bd + ((R0) * 512 + wave * 64) * 8), 16, 0, 0);                 \
    }

#define BAR() asm volatile("s_barrier" ::: "memory")

    // prologue: tiles 0 and 1 fully in flight (12 loads/thread)
    ISSUE_A2(0, 0); ISSUE_A2(0, 2); ISSUE_B1(0, 0); ISSUE_B1(0, 1);
    ISSUE_A2(1, 0); ISSUE_A2(1, 2); ISSUE_B1(1, 0); ISSUE_B1(1, 1);

    for (int kc = 0; kc < 12; ++kc) {
        // boundary: tile kc's 6 loads (oldest) must have landed; kc+1's stay in flight
        if (kc < 11) { asm volatile("s_waitcnt vmcnt(6)" ::: "memory"); }
        else         { asm volatile("s_waitcnt vmcnt(0)" ::: "memory"); }
        BAR();
        const __bf16* Ac = Abuf + (kc % 3) * 16384;
        const __bf16* Bc = Bbuf + (kc % 3) * 8192;
        const bool pf = (kc + 2 < 12);

        bf16x8 af[4], bfr[2];
        // ---- phase 0: ks=0, n-half 0 ----
#pragma unroll
        for (int mt = 0; mt < 4; ++mt) {
            int m = wm + mt * 16 + lane15;
            af[mt] = *(const bf16x8*)(Ac + m * 64 + (quad ^ (m & 7)) * 8);
        }
#pragma unroll
        for (int nt = 0; nt < 2; ++nt) {
            int n = wn + nt * 16 + lane15;
            bfr[nt] = *(const bf16x8*)(Bc + n * 64 + (quad ^ (n & 7)) * 8);
        }
        if (pf) ISSUE_A2(kc + 2, 0);
        BAR();
        __builtin_amdgcn_s_setprio(1);
#pragma unroll
        for (int mt = 0; mt < 4; ++mt)
#pragma unroll
            for (int nt = 0; nt < 2; ++nt)
                acc[mt][nt] = __builtin_amdgcn_mfma_f32_16x16x32_bf16(af[mt], bfr[nt], acc[mt][nt], 0, 0, 0);
        __builtin_amdgcn_s_setprio(0);

        // ---- phase 1: ks=0, n-half 1 (af reused) ----
#pragma unroll
        for (int nt = 0; nt < 2; ++nt) {
            int n = wn + (2 + nt) * 16 + lane15;
            bfr[nt] = *(const bf16x8*)(Bc + n * 64 + (quad ^ (n & 7)) * 8);
        }
        if (pf) ISSUE_A2(kc + 2, 2);
        BAR();
        __builtin_amdgcn_s_setprio(1);
#pragma unroll
        for (int mt = 0; mt < 4; ++mt)
#pragma unroll
            for (int nt = 0; nt < 2; ++nt)
                acc[mt][2 + nt] = __builtin_amdgcn_mfma_f32_16x16x32_bf16(af[mt], bfr[nt], acc[mt][2 + nt], 0, 0, 0);
        __builtin_amdgcn_s_setprio(0);

        // ---- phase 2: ks=1, n-half 0 ----
#pragma unroll
        for (int mt = 0; mt < 4; ++mt) {
            int m = wm + mt * 16 + lane15;
            af[mt] = *(const bf16x8*)(Ac + m * 64 + ((4 + quad) ^ (m & 7)) * 8);
        }
#pragma unroll
        for (int nt = 0; nt < 2; ++nt) {
            int n = wn + nt * 16 + lane15;
            bfr[nt] = *(const bf16x8*)(Bc + n * 64 + ((4 + quad) ^ (n & 7)) * 8);
        }
        if (pf) ISSUE_B1(kc + 2, 0);
        BAR();
        __builtin_amdgcn_s_setprio(1);
#pragma unroll
        for (int mt = 0; mt < 4; ++mt)
#pragma unroll
            for (int nt = 0; nt < 2; ++nt)
                acc[mt][nt] = __builtin_amdgcn_mfma_f32_16x16x32_bf16(af[mt], bfr[nt], acc[mt][nt], 0, 0, 0);
        __builtin_amdgcn_s_setprio(0);

        // ---- phase 3: ks=1, n-half 1 (af reused) ----
#pragma unroll
        for (int nt = 0; nt < 2; ++nt) {
            int n = wn + (2 + nt) * 16 + lane15;
            bfr[nt] = *(const bf16x8*)(Bc + n * 64 + ((4 + quad) ^ (n & 7)) * 8);
        }
        if (pf) ISSUE_B1(kc + 2, 1);
        BAR();
        __builtin_amdgcn_s_setprio(1);
#pragma unroll
        for (int mt = 0; mt < 4; ++mt)
#pragma unroll
            for (int nt = 0; nt < 2; ++nt)
                acc[mt][2 + nt] = __builtin_amdgcn_mfma_f32_16x16x32_bf16(af[mt], bfr[nt], acc[mt][2 + nt], 0, 0, 0);
        __builtin_amdgcn_s_setprio(0);
    }

    if (n0 < 1536) {
        const bool isq = (n0 < 768);
        const float sc = isq ? (0.125f * LOG2E) : 1.0f;
#pragma unroll
        for (int nt = 0; nt < 4; ++nt) {
            int n = n0 + wn + nt * 16 + lane15;
            int rem = isq ? n : (n - 768);
            int h = rem >> 6;
            int d = n & 63;
            float bv = bias[n];
            __bf16* dst = isq ? qb : kb;
#pragma unroll
            for (int mt = 0; mt < 4; ++mt) {
#pragma unroll
                for (int reg = 0; reg < 4; ++reg) {
                    int mr = m0 + wm + mt * 16 + quad * 4 + reg;
                    int bb = mr >> 10, t = mr & 1023;
                    dst[(((size_t)bb * H_ + h) * T_ + t) * D_ + d] =
                        (__bf16)((acc[mt][nt][reg] + bv) * sc);
                }
            }
        }
    } else {
        // v block: transpose through LDS; store with within-64-key permutation
        // storage position s (0..63) holds key t_local = (s&3)*16 + (s>>2)
        __syncthreads();   // drain all waves' K-loop LDS reads before reuse
        __bf16* vls = smem;  // [128 n][264]  (33792 elems <= 73728)
#pragma unroll
        for (int nt = 0; nt < 4; ++nt) {
            int nl = wn + nt * 16 + lane15;
            float bv = bias[n0 + nl];
#pragma unroll
            for (int mt = 0; mt < 4; ++mt)
#pragma unroll
                for (int reg = 0; reg < 4; ++reg)
                    vls[nl * 264 + wm + mt * 16 + quad * 4 + reg] =
                        (__bf16)(acc[mt][nt][reg] + bv);
        }
        __syncthreads();
        int nl = tid >> 2;
        int t0 = (tid & 3) * 64;
        int n = n0 + nl;
        int h = (n - 1536) >> 6;
        int d = n & 63;
        int bb = m0 >> 10, tg = (m0 & 1023) + t0;
        __bf16* dst = vbt + (((size_t)bb * H_ + h) * D_ + d) * T_ + tg;
        const __bf16* srcl = vls + nl * 264 + t0;
#pragma unroll
        for (int c = 0; c < 8; ++c) {
            bf16x8 v;
#pragma unroll
            for (int i = 0; i < 8; ++i) {
                int s = c * 8 + i;
                v[i] = srcl[(s & 3) * 16 + (s >> 2)];
            }
            *(bf16x8*)(dst + c * 8) = v;
        }
    }
#undef ISSUE_A2
#undef ISSUE_B1
#undef BAR
}

// ---------------- proj GEMM v5 (round-2 proven): 128M x 64N, BK=64, single-buffer LDS ----------------
__global__ __launch_bounds__(256) void proj_gemm_mfma(const __bf16* __restrict__ A,
                                                      const __bf16* __restrict__ Bt,
                                                      const float* __restrict__ bias,
                                                      float* __restrict__ out) {
    __shared__ __bf16 As[128 * 64];
    __shared__ __bf16 Bs[64 * 64];
    const int tid = threadIdx.x;
    const int wave = tid >> 6, lane = tid & 63;
    const int lane15 = lane & 15, quad = lane >> 4;
    const int bid = blockIdx.x;
    const int m0 = ((bid & 7) * 8 + ((bid >> 3) & 7)) * 128;
    const int n0 = (bid >> 6) * 64;
    const int wm = wave * 32;
    f32x4 acc[2][4] = {};

#define PSTAGE(KC)                                                                  \
    {                                                                               \
        const int k0s = (KC) * 64;                                                  \
        _Pragma("unroll")                                                           \
        for (int r = 0; r < 4; ++r) {                                               \
            int p = r * 256 + tid;                                                  \
            int mrow = p >> 3, csw = p & 7;                                         \
            int ksrc = (csw ^ (mrow & 7)) * 8;                                      \
            __builtin_amdgcn_global_load_lds(                                       \
                (gptr_t)(A + (size_t)(m0 + mrow) * 768 + k0s + ksrc),               \
                (lptr_t)(&As[0] + (r * 256 + wave * 64) * 8), 16, 0, 0);            \
        }                                                                           \
        _Pragma("unroll")                                                           \
        for (int r = 0; r < 2; ++r) {                                               \
            int p = r * 256 + tid;                                                  \
            int nrow = p >> 3, csw = p & 7;                                         \
            int ksrc = (csw ^ (nrow & 7)) * 8;                                      \
            __builtin_amdgcn_global_load_lds(                                       \
                (gptr_t)(Bt + (size_t)(n0 + nrow) * 768 + k0s + ksrc),              \
                (lptr_t)(&Bs[0] + (r * 256 + wave * 64) * 8), 16, 0, 0);            \
        }                                                                           \
    }

    for (int kc = 0; kc < 12; ++kc) {
        PSTAGE(kc);
        __syncthreads();
#pragma unroll
        for (int ks = 0; ks < 2; ++ks) {
            bf16x8 af[2], bf[4];
#pragma unroll
            for (int mt = 0; mt < 2; ++mt) {
                int m = wm + mt * 16 + lane15;
                int csw = (ks * 4 + quad) ^ (m & 7);
                af[mt] = *(const bf16x8*)(&As[0] + m * 64 + csw * 8);
            }
#pragma unroll
            for (int nt = 0; nt < 4; ++nt) {
                int n = nt * 16 + lane15;
                int csw = (ks * 4 + quad) ^ (n & 7);
                bf[nt] = *(const bf16x8*)(&Bs[0] + n * 64 + csw * 8);
            }
#pragma unroll
            for (int mt = 0; mt < 2; ++mt)
#pragma unroll
                for (int nt = 0; nt < 4; ++nt)
                    acc[mt][nt] = __builtin_amdgcn_mfma_f32_16x16x32_bf16(af[mt], bf[nt], acc[mt][nt], 0, 0, 0);
        }
        __syncthreads();
    }

#pragma unroll
    for (int nt = 0; nt < 4; ++nt) {
        int n = n0 + nt * 16 + lane15;
        float bv = bias[n];
#pragma unroll
        for (int mt = 0; mt < 2; ++mt) {
#pragma unroll
            for (int reg = 0; reg < 4; ++reg) {
                int mr = m0 + wm + mt * 16 + quad * 4 + reg;
                out[(size_t)mr * C_ + n] = acc[mt][nt][reg] + bv;
            }
        }
    }
#undef PSTAGE
}

// ---------------- MFMA flash attention v9: v6 pairing, NO K/V staging (L2-direct), zero barriers ----------------
// Common-mistake #7 / m169: K/V = 256KB/head is L2-resident; LDS staging is pure
// overhead (per-unit __syncthreads + vmcnt drain). The staging swizzle cancels:
//   kf0 = K[(k0+row)*64 + quad*8], kf1 = +32;  vf = V[row*1024 + k0 + (half*4+quad)*8]
// (16B-aligned; each wave-instruction pair fully consumes every touched 128B line).
// V loads issued before QK so their L2 latency hides under QK+softmax; 12 waves/CU
// drift freely (no barriers anywhere). Ps stays wave-private in LDS (9KB;
// write->read ordered by compiler lgkmcnt). Balanced pairing (15-y, y) = 17
// units/block, grid (96,8) unchanged.
__global__ __launch_bounds__(256) void attn_mfma(const __bf16* __restrict__ qb,
                                                 const __bf16* __restrict__ kb,
                                                 const __bf16* __restrict__ vbt,
                                                 __bf16* __restrict__ ao) {
    __shared__ __bf16 Ps[4 * 16 * 72];

    const int tid = threadIdx.x;
    const int wave = tid >> 6, lane = tid & 63;
    const int lane15 = lane & 15, quad = lane >> 4;
    const int bh = blockIdx.x;
    const int y = blockIdx.y;
    const int qtA = 15 - y;            // long segment: 8..15
    const int qtB = y;                 // short segment: 0..7
    const int kuA = qtA + 1;           // 9..16 units
    const int UT = 17;                 // kuA + (qtB+1) == 17 always
    const int b = bh / H_, h = bh % H_;

    const __bf16* Kb = kb + (size_t)bh * T_ * D_;
    const __bf16* Vb = vbt + (size_t)bh * D_ * T_;
    __bf16* Pw = Ps + wave * 16 * 72;

    // Q fragments for both segments (wave owns 16 q-rows per segment)
    bf16x8 qfA[2], qfB[2];
    {
        const __bf16* qrA = qb + ((size_t)bh * T_ + qtA * 64 + wave * 16 + lane15) * D_ + quad * 8;
        qfA[0] = *(const bf16x8*)qrA;
        qfA[1] = *(const bf16x8*)(qrA + 32);
        const __bf16* qrB = qb + ((size_t)bh * T_ + qtB * 64 + wave * 16 + lane15) * D_ + quad * 8;
        qfB[0] = *(const bf16x8*)qrB;
        qfB[1] = *(const bf16x8*)(qrB + 32);
    }

    f32x4 o[4] = {};
    float lsum[4] = {0.f, 0.f, 0.f, 0.f};

    for (int u = 0; u < UT; ++u) {
        const int seg = (u >= kuA) ? 1 : 0;
        const int qt = seg ? qtB : qtA;
        const int k0 = (seg ? (u - kuA) : u) * 64;

        const bf16x8 q0r = seg ? qfB[0] : qfA[0];
        const bf16x8 q1r = seg ? qfB[1] : qfA[1];

        // ---- V fragments: issue FIRST so L2 latency hides under QK + softmax ----
        bf16x8 vf[4][2];
#pragma unroll
        for (int dt = 0; dt < 4; ++dt) {
            int row = dt * 16 + lane15;
#pragma unroll
            for (int half = 0; half < 2; ++half)
                vf[dt][half] = *(const bf16x8*)(Vb + (size_t)row * T_ + k0 + (half * 4 + quad) * 8);
        }

        // ---- QK: K fragments direct from L2, transient per kt ----
        f32x4 s[4];
        __builtin_amdgcn_s_setprio(1);
#pragma unroll
        for (int kt = 0; kt < 4; ++kt) {
            int row = kt * 16 + lane15;
            bf16x8 kf0 = *(const bf16x8*)(Kb + (size_t)(k0 + row) * D_ + quad * 8);
            bf16x8 kf1 = *(const bf16x8*)(Kb + (size_t)(k0 + row) * D_ + 32 + quad * 8);
            f32x4 t = {};
            t = __builtin_amdgcn_mfma_f32_16x16x32_bf16(q0r, kf0, t, 0, 0, 0);
            t = __builtin_amdgcn_mfma_f32_16x16x32_bf16(q1r, kf1, t, 0, 0, 0);
            s[kt] = t;
        }
        __builtin_amdgcn_s_setprio(0);

        const bool diag = (k0 == qt * 64);
#pragma unroll
        for (int r = 0; r < 4; ++r) {
            bf16x4 pk;
#pragma unroll
            for (int kt = 0; kt < 4; ++kt) {
                int col = k0 + kt * 16 + lane15;
                float p = __builtin_amdgcn_exp2f(s[kt][r]);
                if (diag) {
                    int qrow = qt * 64 + wave * 16 + quad * 4 + r;
                    if (col > qrow) p = 0.f;
                }
                lsum[r] += p;
                pk[kt] = (__bf16)p;
            }
            // storage column = lane15*4 + kt  (matches vbt's permuted key order)
            *(bf16x4*)(Pw + (quad * 4 + r) * 72 + lane15 * 4) = pk;
        }

        __builtin_amdgcn_s_setprio(1);
#pragma unroll
        for (int half = 0; half < 2; ++half) {
            bf16x8 pf = *(const bf16x8*)(Pw + lane15 * 72 + half * 32 + quad * 8);
#pragma unroll
            for (int dt = 0; dt < 4; ++dt)
                o[dt] = __builtin_amdgcn_mfma_f32_16x16x32_bf16(pf, vf[dt][half], o[dt], 0, 0, 0);
        }
        __builtin_amdgcn_s_setprio(0);

        // segment finalize (block-uniform condition)
        if (u == kuA - 1 || u == UT - 1) {
            const int q0 = qt * 64;
            float inv[4];
#pragma unroll
            for (int r = 0; r < 4; ++r) {
                float ls = lsum[r];
                ls += __shfl_xor(ls, 1);
                ls += __shfl_xor(ls, 2);
                ls += __shfl_xor(ls, 4);
                ls += __shfl_xor(ls, 8);
                inv[r] = 1.0f / ls;
                lsum[r] = 0.f;
            }
#pragma unroll
            for (int dt = 0; dt < 4; ++dt) {
#pragma unroll
                for (int r = 0; r < 4; ++r) {
                    int t = q0 + wave * 16 + quad * 4 + r;
                    ao[((size_t)(b * T_ + t)) * C_ + h * 64 + dt * 16 + lane15] =
                        (__bf16)(o[dt][r] * inv[r]);
                }
                o[dt] = f32x4{};
            }
        }
    }
}

extern "C" void kernel_launch(void* const* d_in, const int* in_sizes, int n_in,
                              void* d_out, int out_size, void* d_ws, size_t ws_size,
                              hipStream_t stream) {
    const float* x = (const float*)d_in[0];
    const float* w_attn = (const float*)d_in[1];
    const float* b_attn = (const float*)d_in[2];
    const float* w_proj = (const float*)d_in[3];
    const float* b_proj = (const float*)d_in[4];
    float* out = (float*)d_out;

    __bf16* xb = (__bf16*)d_ws;
    __bf16* wat = xb + (size_t)M_ * C_;
    __bf16* wpt = wat + (size_t)N3C * C_;
    __bf16* qb = wpt + (size_t)C_ * C_;         // pre-scaled by (1/8)log2e
    __bf16* kb = qb + (size_t)96 * T_ * D_;
    __bf16* vbt = kb + (size_t)96 * T_ * D_;    // [96][64][1024], permuted keys
    __bf16* ao = vbt + (size_t)96 * T_ * D_;

    prepass<<<5376, 256, 0, stream>>>(x, xb, w_attn, wat, w_proj, wpt);
    qkv_gemm_mfma<<<576, 512, 0, stream>>>(xb, wat, b_attn, qb, kb, vbt);
    attn_mfma<<<dim3(96, 8), 256, 0, stream>>>(qb, kb, vbt, ao);
    proj_gemm_mfma<<<768, 256, 0, stream>>>(ao, wpt, b_proj, out);
}

// Round 11
// 180.056 us; speedup vs baseline: 1.3490x; 1.3490x over previous
//
#include <hip/hip_runtime.h>
#include <hip/hip_bf16.h>
#include <cmath>

// B=8, T=1024, C=768, H=12, D=64
#define B_ 8
#define T_ 1024
#define C_ 768
#define H_ 12
#define D_ 64
#define N3C 2304
#define M_ 8192   // B*T

typedef __bf16 bf16x4 __attribute__((ext_vector_type(4)));
typedef __bf16 bf16x8 __attribute__((ext_vector_type(8)));
typedef float  f32x4  __attribute__((ext_vector_type(4)));

typedef const __attribute__((address_space(1))) void* gptr_t;
typedef __attribute__((address_space(3))) void* lptr_t;

#define LOG2E 1.44269504088896f

__device__ __forceinline__ bf16x8 cvt_bf16x8(const float4& a, const float4& b) {
    bf16x8 r;
    r[0] = (__bf16)a.x; r[1] = (__bf16)a.y; r[2] = (__bf16)a.z; r[3] = (__bf16)a.w;
    r[4] = (__bf16)b.x; r[5] = (__bf16)b.y; r[6] = (__bf16)b.z; r[7] = (__bf16)b.w;
    return r;
}

// ---------------- fused pre-pass: cast x + transpose-cast both weights ----------------
__global__ __launch_bounds__(256) void prepass(const float* __restrict__ x,
                                               __bf16* __restrict__ xb,
                                               const float* __restrict__ wa,
                                               __bf16* __restrict__ wat,
                                               const float* __restrict__ wp,
                                               __bf16* __restrict__ wpt) {
    __shared__ float tile[32][33];
    const int bx = blockIdx.x, tid = threadIdx.x;
    if (bx < 3072) {
        int i = (bx * 256 + tid) * 8;
        float4 a = *(const float4*)&x[i];
        float4 b = *(const float4*)&x[i + 4];
        *(bf16x8*)&xb[i] = cvt_bf16x8(a, b);
        return;
    }
    const float* w;
    __bf16* wt;
    int K, N, n0, k0;
    if (bx < 4800) {
        int bb = bx - 3072;           // w_attn: 72 n-tiles x 24 k-tiles
        w = wa; wt = wat; K = 768; N = 2304;
        n0 = (bb % 72) * 32; k0 = (bb / 72) * 32;
    } else {
        int bb = bx - 4800;           // w_proj: 24 x 24 tiles
        w = wp; wt = wpt; K = 768; N = 768;
        n0 = (bb % 24) * 32; k0 = (bb / 24) * 32;
    }
    int tx = tid & 31, ty = tid >> 5;
#pragma unroll
    for (int i = 0; i < 4; i++)
        tile[ty + i * 8][tx] = w[(size_t)(k0 + ty + i * 8) * N + n0 + tx];
    __syncthreads();
#pragma unroll
    for (int i = 0; i < 4; i++)
        wt[(size_t)(n0 + ty + i * 8) * K + k0 + tx] = (__bf16)tile[tx][ty + i * 8];
}

// ---------------- QKV GEMM v7b: 256x128, BK=64, 8 waves, 2-phase (16 MFMA/barrier) + counted vmcnt ----------------
// Midpoint between v6 (4-phase, 8 MFMA/barrier, 44.4us) and round-3's failed full
// coarsening (32 MFMA, 1 barrier, -7%). Per K-step: boundary {vmcnt(6); barrier},
// then 2 phases of {8 ds_read_b128 || issue prefetch chunk -> barrier -> setprio(1)
// -> 16 MFMA -> setprio(0)}. m201's proven phase shape is exactly 16 MFMA/phase.
// Triple-buffer + vmcnt accounting identical to v6 (6 loads/K-step: A x4 in phase 0,
// B x2 in phase 1; target buf (kc+2)%3 last read at kc-1, issue is after boundary
// barrier of kc -> safe).
__global__ __launch_bounds__(512, 2) void qkv_gemm_mfma(const __bf16* __restrict__ A,
                                                        const __bf16* __restrict__ Bt,
                                                        const float* __restrict__ bias,
                                                        __bf16* __restrict__ qb,
                                                        __bf16* __restrict__ kb,
                                                        __bf16* __restrict__ vbt) {
    __shared__ __bf16 smem[73728];               // 144KB: A 3x16384 | B 3x8192; epilogue reuses
    __bf16* Abuf = smem;
    __bf16* Bbuf = smem + 49152;
    const int tid = threadIdx.x;
    const int wave = tid >> 6, lane = tid & 63;
    const int lane15 = lane & 15, quad = lane >> 4;
    // XCD-chunked swizzle: 576 blocks, 72 per XCD, n-major within chunk (B panel L2-resident)
    const int swz = (blockIdx.x & 7) * 72 + (blockIdx.x >> 3);
    const int n0 = (swz % 18) * 128;
    const int m0 = (swz / 18) * 256;
    const int wm = (wave >> 1) * 64, wn = (wave & 1) * 64;
    f32x4 acc[4][4] = {};

#define ISSUE_A2(KC, R0)                                                            \
    {                                                                               \
        const int k0s = (KC) * 64;                                                  \
        __bf16* Ad = Abuf + ((KC) % 3) * 16384;                                     \
        _Pragma("unroll")                                                           \
        for (int r = (R0); r < (R0) + 2; ++r) {                                     \
            int p = r * 512 + tid;                                                  \
            int row = p >> 3, csw = p & 7;                                          \
            __builtin_amdgcn_global_load_lds(                                       \
                (gptr_t)(A + (size_t)(m0 + row) * 768 + k0s + (csw ^ (row & 7)) * 8), \
                (lptr_t)(Ad + (r * 512 + wave * 64) * 8), 16, 0, 0);                \
        }                                                                           \
    }

#define ISSUE_B1(KC, R0)                                                            \
    {                                                                               \
        const int k0s = (KC) * 64;                                                  \
        __bf16* Bd = Bbuf + ((KC) % 3) * 8192;                                      \
        int p = (R0) * 512 + tid;                                                   \
        int row = p >> 3, csw = p & 7;                                              \
        __builtin_amdgcn_global_load_lds(                                           \
            (gptr_t)(Bt + (size_t)(n0 + row) * 768 + k0s + (csw ^ (row & 7)) * 8),  \
            (lptr_t)(Bd + ((R0) * 512 + wave * 64) * 8), 16, 0, 0);                 \
    }

#define BAR() asm volatile("s_barrier" ::: "memory")

    // prologue: tiles 0 and 1 fully in flight (12 loads/thread)
    ISSUE_A2(0, 0); ISSUE_A2(0, 2); ISSUE_B1(0, 0); ISSUE_B1(0, 1);
    ISSUE_A2(1, 0); ISSUE_A2(1, 2); ISSUE_B1(1, 0); ISSUE_B1(1, 1);

    for (int kc = 0; kc < 12; ++kc) {
        // boundary: tile kc's 6 loads (oldest) must have landed; kc+1's stay in flight
        if (kc < 11) { asm volatile("s_waitcnt vmcnt(6)" ::: "memory"); }
        else         { asm volatile("s_waitcnt vmcnt(0)" ::: "memory"); }
        BAR();
        const __bf16* Ac = Abuf + (kc % 3) * 16384;
        const __bf16* Bc = Bbuf + (kc % 3) * 8192;
        const bool pf = (kc + 2 < 12);

        bf16x8 af[4], bfr[4];
        // ---- phase 0: ks=0, all 16 MFMA ----
#pragma unroll
        for (int mt = 0; mt < 4; ++mt) {
            int m = wm + mt * 16 + lane15;
            af[mt] = *(const bf16x8*)(Ac + m * 64 + (quad ^ (m & 7)) * 8);
        }
#pragma unroll
        for (int nt = 0; nt < 4; ++nt) {
            int n = wn + nt * 16 + lane15;
            bfr[nt] = *(const bf16x8*)(Bc + n * 64 + (quad ^ (n & 7)) * 8);
        }
        if (pf) { ISSUE_A2(kc + 2, 0); ISSUE_A2(kc + 2, 2); }
        BAR();
        __builtin_amdgcn_s_setprio(1);
#pragma unroll
        for (int mt = 0; mt < 4; ++mt)
#pragma unroll
            for (int nt = 0; nt < 4; ++nt)
                acc[mt][nt] = __builtin_amdgcn_mfma_f32_16x16x32_bf16(af[mt], bfr[nt], acc[mt][nt], 0, 0, 0);
        __builtin_amdgcn_s_setprio(0);

        // ---- phase 1: ks=1, all 16 MFMA ----
#pragma unroll
        for (int mt = 0; mt < 4; ++mt) {
            int m = wm + mt * 16 + lane15;
            af[mt] = *(const bf16x8*)(Ac + m * 64 + ((4 + quad) ^ (m & 7)) * 8);
        }
#pragma unroll
        for (int nt = 0; nt < 4; ++nt) {
            int n = wn + nt * 16 + lane15;
            bfr[nt] = *(const bf16x8*)(Bc + n * 64 + ((4 + quad) ^ (n & 7)) * 8);
        }
        if (pf) { ISSUE_B1(kc + 2, 0); ISSUE_B1(kc + 2, 1); }
        BAR();
        __builtin_amdgcn_s_setprio(1);
#pragma unroll
        for (int mt = 0; mt < 4; ++mt)
#pragma unroll
            for (int nt = 0; nt < 4; ++nt)
                acc[mt][nt] = __builtin_amdgcn_mfma_f32_16x16x32_bf16(af[mt], bfr[nt], acc[mt][nt], 0, 0, 0);
        __builtin_amdgcn_s_setprio(0);
    }

    if (n0 < 1536) {
        const bool isq = (n0 < 768);
        const float sc = isq ? (0.125f * LOG2E) : 1.0f;
#pragma unroll
        for (int nt = 0; nt < 4; ++nt) {
            int n = n0 + wn + nt * 16 + lane15;
            int rem = isq ? n : (n - 768);
            int h = rem >> 6;
            int d = n & 63;
            float bv = bias[n];
            __bf16* dst = isq ? qb : kb;
#pragma unroll
            for (int mt = 0; mt < 4; ++mt) {
#pragma unroll
                for (int reg = 0; reg < 4; ++reg) {
                    int mr = m0 + wm + mt * 16 + quad * 4 + reg;
                    int bb = mr >> 10, t = mr & 1023;
                    dst[(((size_t)bb * H_ + h) * T_ + t) * D_ + d] =
                        (__bf16)((acc[mt][nt][reg] + bv) * sc);
                }
            }
        }
    } else {
        // v block: transpose through LDS; store with within-64-key permutation
        // storage position s (0..63) holds key t_local = (s&3)*16 + (s>>2)
        __syncthreads();   // drain all waves' K-loop LDS reads before reuse
        __bf16* vls = smem;  // [128 n][264]  (33792 elems <= 73728)
#pragma unroll
        for (int nt = 0; nt < 4; ++nt) {
            int nl = wn + nt * 16 + lane15;
            float bv = bias[n0 + nl];
#pragma unroll
            for (int mt = 0; mt < 4; ++mt)
#pragma unroll
                for (int reg = 0; reg < 4; ++reg)
                    vls[nl * 264 + wm + mt * 16 + quad * 4 + reg] =
                        (__bf16)(acc[mt][nt][reg] + bv);
        }
        __syncthreads();
        int nl = tid >> 2;
        int t0 = (tid & 3) * 64;
        int n = n0 + nl;
        int h = (n - 1536) >> 6;
        int d = n & 63;
        int bb = m0 >> 10, tg = (m0 & 1023) + t0;
        __bf16* dst = vbt + (((size_t)bb * H_ + h) * D_ + d) * T_ + tg;
        const __bf16* srcl = vls + nl * 264 + t0;
#pragma unroll
        for (int c = 0; c < 8; ++c) {
            bf16x8 v;
#pragma unroll
            for (int i = 0; i < 8; ++i) {
                int s = c * 8 + i;
                v[i] = srcl[(s & 3) * 16 + (s >> 2)];
            }
            *(bf16x8*)(dst + c * 8) = v;
        }
    }
#undef ISSUE_A2
#undef ISSUE_B1
#undef BAR
}

// ---------------- proj GEMM v5 (round-2 proven): 128M x 64N, BK=64, single-buffer LDS ----------------
__global__ __launch_bounds__(256) void proj_gemm_mfma(const __bf16* __restrict__ A,
                                                      const __bf16* __restrict__ Bt,
                                                      const float* __restrict__ bias,
                                                      float* __restrict__ out) {
    __shared__ __bf16 As[128 * 64];
    __shared__ __bf16 Bs[64 * 64];
    const int tid = threadIdx.x;
    const int wave = tid >> 6, lane = tid & 63;
    const int lane15 = lane & 15, quad = lane >> 4;
    const int bid = blockIdx.x;
    const int m0 = ((bid & 7) * 8 + ((bid >> 3) & 7)) * 128;
    const int n0 = (bid >> 6) * 64;
    const int wm = wave * 32;
    f32x4 acc[2][4] = {};

#define PSTAGE(KC)                                                                  \
    {                                                                               \
        const int k0s = (KC) * 64;                                                  \
        _Pragma("unroll")                                                           \
        for (int r = 0; r < 4; ++r) {                                               \
            int p = r * 256 + tid;                                                  \
            int mrow = p >> 3, csw = p & 7;                                         \
            int ksrc = (csw ^ (mrow & 7)) * 8;                                      \
            __builtin_amdgcn_global_load_lds(                                       \
                (gptr_t)(A + (size_t)(m0 + mrow) * 768 + k0s + ksrc),               \
                (lptr_t)(&As[0] + (r * 256 + wave * 64) * 8), 16, 0, 0);            \
        }                                                                           \
        _Pragma("unroll")                                                           \
        for (int r = 0; r < 2; ++r) {                                               \
            int p = r * 256 + tid;                                                  \
            int nrow = p >> 3, csw = p & 7;                                         \
            int ksrc = (csw ^ (nrow & 7)) * 8;                                      \
            __builtin_amdgcn_global_load_lds(                                       \
                (gptr_t)(Bt + (size_t)(n0 + nrow) * 768 + k0s + ksrc),              \
                (lptr_t)(&Bs[0] + (r * 256 + wave * 64) * 8), 16, 0, 0);            \
        }                                                                           \
    }

    for (int kc = 0; kc < 12; ++kc) {
        PSTAGE(kc);
        __syncthreads();
#pragma unroll
        for (int ks = 0; ks < 2; ++ks) {
            bf16x8 af[2], bf[4];
#pragma unroll
            for (int mt = 0; mt < 2; ++mt) {
                int m = wm + mt * 16 + lane15;
                int csw = (ks * 4 + quad) ^ (m & 7);
                af[mt] = *(const bf16x8*)(&As[0] + m * 64 + csw * 8);
            }
#pragma unroll
            for (int nt = 0; nt < 4; ++nt) {
                int n = nt * 16 + lane15;
                int csw = (ks * 4 + quad) ^ (n & 7);
                bf[nt] = *(const bf16x8*)(&Bs[0] + n * 64 + csw * 8);
            }
#pragma unroll
            for (int mt = 0; mt < 2; ++mt)
#pragma unroll
                for (int nt = 0; nt < 4; ++nt)
                    acc[mt][nt] = __builtin_amdgcn_mfma_f32_16x16x32_bf16(af[mt], bf[nt], acc[mt][nt], 0, 0, 0);
        }
        __syncthreads();
    }

#pragma unroll
    for (int nt = 0; nt < 4; ++nt) {
        int n = n0 + nt * 16 + lane15;
        float bv = bias[n];
#pragma unroll
        for (int mt = 0; mt < 2; ++mt) {
#pragma unroll
            for (int reg = 0; reg < 4; ++reg) {
                int mr = m0 + wm + mt * 16 + quad * 4 + reg;
                out[(size_t)mr * C_ + n] = acc[mt][nt][reg] + bv;
            }
        }
    }
#undef PSTAGE
}

// ---------------- MFMA flash attention v6 (reverted best; round-10's L2-direct v9 was 5% MfmaUtil, latency-bound) ----------------
// 64-row q-tiles (16 total, kunits = qt+1). Each block handles the PAIR (15-y, y):
// kunits sum = 17 for EVERY block -> perfectly balanced grid. Grid (96,8); LDS 41KB
// -> 3 blocks/CU. The global_load_lds double-buffer IS the prefetch pipeline —
// do not remove it (round 10: -60%).
__global__ __launch_bounds__(256) void attn_mfma(const __bf16* __restrict__ qb,
                                                 const __bf16* __restrict__ kb,
                                                 const __bf16* __restrict__ vbt,
                                                 __bf16* __restrict__ ao) {
    __shared__ __bf16 Ks[2][64 * 64];
    __shared__ __bf16 Vts[2][64 * 64];
    __shared__ __bf16 Ps[4 * 16 * 72];

    const int tid = threadIdx.x;
    const int wave = tid >> 6, lane = tid & 63;
    const int lane15 = lane & 15, quad = lane >> 4;
    const int bh = blockIdx.x;
    const int y = blockIdx.y;
    const int qtA = 15 - y;            // long segment: 8..15
    const int qtB = y;                 // short segment: 0..7
    const int kuA = qtA + 1;           // 9..16 units
    const int UT = 17;                 // kuA + (qtB+1) == 17 always
    const int b = bh / H_, h = bh % H_;

    const __bf16* Kb = kb + (size_t)bh * T_ * D_;
    const __bf16* Vb = vbt + (size_t)bh * D_ * T_;
    __bf16* Pw = Ps + wave * 16 * 72;

    // Q fragments for both segments (wave owns 16 q-rows per segment)
    bf16x8 qfA[2], qfB[2];
    {
        const __bf16* qrA = qb + ((size_t)bh * T_ + qtA * 64 + wave * 16 + lane15) * D_ + quad * 8;
        qfA[0] = *(const bf16x8*)qrA;
        qfA[1] = *(const bf16x8*)(qrA + 32);
        const __bf16* qrB = qb + ((size_t)bh * T_ + qtB * 64 + wave * 16 + lane15) * D_ + quad * 8;
        qfB[0] = *(const bf16x8*)qrB;
        qfB[1] = *(const bf16x8*)(qrB + 32);
    }

    f32x4 o[4] = {};
    float lsum[4] = {0.f, 0.f, 0.f, 0.f};

#define ASTAGE(K0S, BUF)                                                           \
    {                                                                              \
        const int k0s = (K0S);                                                     \
        _Pragma("unroll")                                                          \
        for (int r = 0; r < 2; ++r) {                                              \
            int p = r * 256 + tid;                                                 \
            int row = p >> 3, c = p & 7;                                           \
            int cs = (c ^ (row & 7)) * 8;                                          \
            __builtin_amdgcn_global_load_lds(                                      \
                (gptr_t)(Kb + (size_t)(k0s + row) * D_ + cs),                      \
                (lptr_t)(&Ks[BUF][0] + (r * 256 + wave * 64) * 8), 16, 0, 0);      \
            __builtin_amdgcn_global_load_lds(                                      \
                (gptr_t)(Vb + (size_t)row * T_ + k0s + cs),                        \
                (lptr_t)(&Vts[BUF][0] + (r * 256 + wave * 64) * 8), 16, 0, 0);     \
        }                                                                          \
    }

    ASTAGE(0, 0);

    for (int u = 0; u < UT; ++u) {
        const int seg = (u >= kuA) ? 1 : 0;
        const int qt = seg ? qtB : qtA;
        const int k0 = (seg ? (u - kuA) : u) * 64;
        __syncthreads();
        if (u + 1 < UT) {
            const int un = u + 1;
            const int k0n = (un < kuA) ? un * 64 : (un - kuA) * 64;
            ASTAGE(k0n, un & 1);
        }
        const __bf16* Kc = &Ks[u & 1][0];
        const __bf16* Vc = &Vts[u & 1][0];

        const bf16x8 q0r = seg ? qfB[0] : qfA[0];
        const bf16x8 q1r = seg ? qfB[1] : qfA[1];

        f32x4 s[4];
        __builtin_amdgcn_s_setprio(1);
#pragma unroll
        for (int kt = 0; kt < 4; ++kt) {
            int row = kt * 16 + lane15;
            bf16x8 kf0 = *(const bf16x8*)(Kc + row * 64 + ((quad) ^ (row & 7)) * 8);
            bf16x8 kf1 = *(const bf16x8*)(Kc + row * 64 + ((4 + quad) ^ (row & 7)) * 8);
            f32x4 t = {};
            t = __builtin_amdgcn_mfma_f32_16x16x32_bf16(q0r, kf0, t, 0, 0, 0);
            t = __builtin_amdgcn_mfma_f32_16x16x32_bf16(q1r, kf1, t, 0, 0, 0);
            s[kt] = t;
        }
        __builtin_amdgcn_s_setprio(0);

        const bool diag = (k0 == qt * 64);
#pragma unroll
        for (int r = 0; r < 4; ++r) {
            bf16x4 pk;
#pragma unroll
            for (int kt = 0; kt < 4; ++kt) {
                int col = k0 + kt * 16 + lane15;
                float p = __builtin_amdgcn_exp2f(s[kt][r]);
                if (diag) {
                    int qrow = qt * 64 + wave * 16 + quad * 4 + r;
                    if (col > qrow) p = 0.f;
                }
                lsum[r] += p;
                pk[kt] = (__bf16)p;
            }
            // storage column = lane15*4 + kt  (matches vbt's permuted key order)
            *(bf16x4*)(Pw + (quad * 4 + r) * 72 + lane15 * 4) = pk;
        }

        bf16x8 vf[4][2];
#pragma unroll
        for (int dt = 0; dt < 4; ++dt) {
            int row = dt * 16 + lane15;
#pragma unroll
            for (int half = 0; half < 2; ++half)
                vf[dt][half] = *(const bf16x8*)(Vc + row * 64 + ((half * 4 + quad) ^ (row & 7)) * 8);
        }
        __builtin_amdgcn_s_setprio(1);
#pragma unroll
        for (int half = 0; half < 2; ++half) {
            bf16x8 pf = *(const bf16x8*)(Pw + lane15 * 72 + half * 32 + quad * 8);
#pragma unroll
            for (int dt = 0; dt < 4; ++dt)
                o[dt] = __builtin_amdgcn_mfma_f32_16x16x32_bf16(pf, vf[dt][half], o[dt], 0, 0, 0);
        }
        __builtin_amdgcn_s_setprio(0);

        // segment finalize (block-uniform condition)
        if (u == kuA - 1 || u == UT - 1) {
            const int q0 = qt * 64;
            float inv[4];
#pragma unroll
            for (int r = 0; r < 4; ++r) {
                float ls = lsum[r];
                ls += __shfl_xor(ls, 1);
                ls += __shfl_xor(ls, 2);
                ls += __shfl_xor(ls, 4);
                ls += __shfl_xor(ls, 8);
                inv[r] = 1.0f / ls;
                lsum[r] = 0.f;
            }
#pragma unroll
            for (int dt = 0; dt < 4; ++dt) {
#pragma unroll
                for (int r = 0; r < 4; ++r) {
                    int t = q0 + wave * 16 + quad * 4 + r;
                    ao[((size_t)(b * T_ + t)) * C_ + h * 64 + dt * 16 + lane15] =
                        (__bf16)(o[dt][r] * inv[r]);
                }
                o[dt] = f32x4{};
            }
        }
    }
#undef ASTAGE
}

extern "C" void kernel_launch(void* const* d_in, const int* in_sizes, int n_in,
                              void* d_out, int out_size, void* d_ws, size_t ws_size,
                              hipStream_t stream) {
    const float* x = (const float*)d_in[0];
    const float* w_attn = (const float*)d_in[1];
    const float* b_attn = (const float*)d_in[2];
    const float* w_proj = (const float*)d_in[3];
    const float* b_proj = (const float*)d_in[4];
    float* out = (float*)d_out;

    __bf16* xb = (__bf16*)d_ws;
    __bf16* wat = xb + (size_t)M_ * C_;
    __bf16* wpt = wat + (size_t)N3C * C_;
    __bf16* qb = wpt + (size_t)C_ * C_;         // pre-scaled by (1/8)log2e
    __bf16* kb = qb + (size_t)96 * T_ * D_;
    __bf16* vbt = kb + (size_t)96 * T_ * D_;    // [96][64][1024], permuted keys
    __bf16* ao = vbt + (size_t)96 * T_ * D_;

    prepass<<<5376, 256, 0, stream>>>(x, xb, w_attn, wat, w_proj, wpt);
    qkv_gemm_mfma<<<576, 512, 0, stream>>>(xb, wat, b_attn, qb, kb, vbt);
    attn_mfma<<<dim3(96, 8), 256, 0, stream>>>(qb, kb, vbt, ao);
    proj_gemm_mfma<<<768, 256, 0, stream>>>(ao, wpt, b_proj, out);
}

// Round 12
// 168.145 us; speedup vs baseline: 1.4445x; 1.0708x over previous
//
#include <hip/hip_runtime.h>
#include <hip/hip_bf16.h>
#include <cmath>

// B=8, T=1024, C=768, H=12, D=64
#define B_ 8
#define T_ 1024
#define C_ 768
#define H_ 12
#define D_ 64
#define N3C 2304
#define M_ 8192   // B*T

typedef __bf16 bf16x4 __attribute__((ext_vector_type(4)));
typedef __bf16 bf16x8 __attribute__((ext_vector_type(8)));
typedef float  f32x4  __attribute__((ext_vector_type(4)));

typedef const __attribute__((address_space(1))) void* gptr_t;
typedef __attribute__((address_space(3))) void* lptr_t;

#define LOG2E 1.44269504088896f

__device__ __forceinline__ bf16x8 cvt_bf16x8(const float4& a, const float4& b) {
    bf16x8 r;
    r[0] = (__bf16)a.x; r[1] = (__bf16)a.y; r[2] = (__bf16)a.z; r[3] = (__bf16)a.w;
    r[4] = (__bf16)b.x; r[5] = (__bf16)b.y; r[6] = (__bf16)b.z; r[7] = (__bf16)b.w;
    return r;
}

// ---------------- fused pre-pass: cast x + transpose-cast both weights ----------------
__global__ __launch_bounds__(256) void prepass(const float* __restrict__ x,
                                               __bf16* __restrict__ xb,
                                               const float* __restrict__ wa,
                                               __bf16* __restrict__ wat,
                                               const float* __restrict__ wp,
                                               __bf16* __restrict__ wpt) {
    __shared__ float tile[32][33];
    const int bx = blockIdx.x, tid = threadIdx.x;
    if (bx < 3072) {
        int i = (bx * 256 + tid) * 8;
        float4 a = *(const float4*)&x[i];
        float4 b = *(const float4*)&x[i + 4];
        *(bf16x8*)&xb[i] = cvt_bf16x8(a, b);
        return;
    }
    const float* w;
    __bf16* wt;
    int K, N, n0, k0;
    if (bx < 4800) {
        int bb = bx - 3072;           // w_attn: 72 n-tiles x 24 k-tiles
        w = wa; wt = wat; K = 768; N = 2304;
        n0 = (bb % 72) * 32; k0 = (bb / 72) * 32;
    } else {
        int bb = bx - 4800;           // w_proj: 24 x 24 tiles
        w = wp; wt = wpt; K = 768; N = 768;
        n0 = (bb % 24) * 32; k0 = (bb / 24) * 32;
    }
    int tx = tid & 31, ty = tid >> 5;
#pragma unroll
    for (int i = 0; i < 4; i++)
        tile[ty + i * 8][tx] = w[(size_t)(k0 + ty + i * 8) * N + n0 + tx];
    __syncthreads();
#pragma unroll
    for (int i = 0; i < 4; i++)
        wt[(size_t)(n0 + ty + i * 8) * K + k0 + tx] = (__bf16)tile[tx][ty + i * 8];
}

// ---------------- QKV GEMM v6 (best: 44.4-45.5us fast-mode, reproduced 4x): 256x128, BK=64, 8 waves, 4-phase + counted vmcnt ----------------
// Triple-buffered LDS (144KB); tile kc+2's 6 loads issued split across tile kc's 4
// phases; boundary vmcnt(6) (never 0 in main loop). Phase = {ds_read frags || issue
// prefetch -> barrier -> setprio(1) -> 8 MFMA -> setprio(0)}.
// Phase-granularity curve (measured): 4-phase 44.4 < 2-phase 46.5 < 1-phase 47.4.
// DO NOT coarsen. DO NOT dbuf-within-2-blocks (round 1: flat).
__global__ __launch_bounds__(512, 2) void qkv_gemm_mfma(const __bf16* __restrict__ A,
                                                        const __bf16* __restrict__ Bt,
                                                        const float* __restrict__ bias,
                                                        __bf16* __restrict__ qb,
                                                        __bf16* __restrict__ kb,
                                                        __bf16* __restrict__ vbt) {
    __shared__ __bf16 smem[73728];               // 144KB: A 3x16384 | B 3x8192; epilogue reuses
    __bf16* Abuf = smem;
    __bf16* Bbuf = smem + 49152;
    const int tid = threadIdx.x;
    const int wave = tid >> 6, lane = tid & 63;
    const int lane15 = lane & 15, quad = lane >> 4;
    // XCD-chunked swizzle: 576 blocks, 72 per XCD, n-major within chunk (B panel L2-resident)
    const int swz = (blockIdx.x & 7) * 72 + (blockIdx.x >> 3);
    const int n0 = (swz % 18) * 128;
    const int m0 = (swz / 18) * 256;
    const int wm = (wave >> 1) * 64, wn = (wave & 1) * 64;
    f32x4 acc[4][4] = {};

#define ISSUE_A2(KC, R0)                                                            \
    {                                                                               \
        const int k0s = (KC) * 64;                                                  \
        __bf16* Ad = Abuf + ((KC) % 3) * 16384;                                     \
        _Pragma("unroll")                                                           \
        for (int r = (R0); r < (R0) + 2; ++r) {                                     \
            int p = r * 512 + tid;                                                  \
            int row = p >> 3, csw = p & 7;                                          \
            __builtin_amdgcn_global_load_lds(                                       \
                (gptr_t)(A + (size_t)(m0 + row) * 768 + k0s + (csw ^ (row & 7)) * 8), \
                (lptr_t)(Ad + (r * 512 + wave * 64) * 8), 16, 0, 0);                \
        }                                                                           \
    }

#define ISSUE_B1(KC, R0)                                                            \
    {                                                                               \
        const int k0s = (KC) * 64;                                                  \
        __bf16* Bd = Bbuf + ((KC) % 3) * 8192;                                      \
        int p = (R0) * 512 + tid;                                                   \
        int row = p >> 3, csw = p & 7;                                              \
        __builtin_amdgcn_global_load_lds(                                           \
            (gptr_t)(Bt + (size_t)(n0 + row) * 768 + k0s + (csw ^ (row & 7)) * 8),  \
            (lptr_t)(Bd + ((R0) * 512 + wave * 64) * 8), 16, 0, 0);                 \
    }

#define BAR() asm volatile("s_barrier" ::: "memory")

    // prologue: tiles 0 and 1 fully in flight (12 loads/thread)
    ISSUE_A2(0, 0); ISSUE_A2(0, 2); ISSUE_B1(0, 0); ISSUE_B1(0, 1);
    ISSUE_A2(1, 0); ISSUE_A2(1, 2); ISSUE_B1(1, 0); ISSUE_B1(1, 1);

    for (int kc = 0; kc < 12; ++kc) {
        // boundary: tile kc's 6 loads (oldest) must have landed; kc+1's stay in flight
        if (kc < 11) { asm volatile("s_waitcnt vmcnt(6)" ::: "memory"); }
        else         { asm volatile("s_waitcnt vmcnt(0)" ::: "memory"); }
        BAR();
        const __bf16* Ac = Abuf + (kc % 3) * 16384;
        const __bf16* Bc = Bbuf + (kc % 3) * 8192;
        const bool pf = (kc + 2 < 12);

        bf16x8 af[4], bfr[2];
        // ---- phase 0: ks=0, n-half 0 ----
#pragma unroll
        for (int mt = 0; mt < 4; ++mt) {
            int m = wm + mt * 16 + lane15;
            af[mt] = *(const bf16x8*)(Ac + m * 64 + (quad ^ (m & 7)) * 8);
        }
#pragma unroll
        for (int nt = 0; nt < 2; ++nt) {
            int n = wn + nt * 16 + lane15;
            bfr[nt] = *(const bf16x8*)(Bc + n * 64 + (quad ^ (n & 7)) * 8);
        }
        if (pf) ISSUE_A2(kc + 2, 0);
        BAR();
        __builtin_amdgcn_s_setprio(1);
#pragma unroll
        for (int mt = 0; mt < 4; ++mt)
#pragma unroll
            for (int nt = 0; nt < 2; ++nt)
                acc[mt][nt] = __builtin_amdgcn_mfma_f32_16x16x32_bf16(af[mt], bfr[nt], acc[mt][nt], 0, 0, 0);
        __builtin_amdgcn_s_setprio(0);

        // ---- phase 1: ks=0, n-half 1 (af reused) ----
#pragma unroll
        for (int nt = 0; nt < 2; ++nt) {
            int n = wn + (2 + nt) * 16 + lane15;
            bfr[nt] = *(const bf16x8*)(Bc + n * 64 + (quad ^ (n & 7)) * 8);
        }
        if (pf) ISSUE_A2(kc + 2, 2);
        BAR();
        __builtin_amdgcn_s_setprio(1);
#pragma unroll
        for (int mt = 0; mt < 4; ++mt)
#pragma unroll
            for (int nt = 0; nt < 2; ++nt)
                acc[mt][2 + nt] = __builtin_amdgcn_mfma_f32_16x16x32_bf16(af[mt], bfr[nt], acc[mt][2 + nt], 0, 0, 0);
        __builtin_amdgcn_s_setprio(0);

        // ---- phase 2: ks=1, n-half 0 ----
#pragma unroll
        for (int mt = 0; mt < 4; ++mt) {
            int m = wm + mt * 16 + lane15;
            af[mt] = *(const bf16x8*)(Ac + m * 64 + ((4 + quad) ^ (m & 7)) * 8);
        }
#pragma unroll
        for (int nt = 0; nt < 2; ++nt) {
            int n = wn + nt * 16 + lane15;
            bfr[nt] = *(const bf16x8*)(Bc + n * 64 + ((4 + quad) ^ (n & 7)) * 8);
        }
        if (pf) ISSUE_B1(kc + 2, 0);
        BAR();
        __builtin_amdgcn_s_setprio(1);
#pragma unroll
        for (int mt = 0; mt < 4; ++mt)
#pragma unroll
            for (int nt = 0; nt < 2; ++nt)
                acc[mt][nt] = __builtin_amdgcn_mfma_f32_16x16x32_bf16(af[mt], bfr[nt], acc[mt][nt], 0, 0, 0);
        __builtin_amdgcn_s_setprio(0);

        // ---- phase 3: ks=1, n-half 1 (af reused) ----
#pragma unroll
        for (int nt = 0; nt < 2; ++nt) {
            int n = wn + (2 + nt) * 16 + lane15;
            bfr[nt] = *(const bf16x8*)(Bc + n * 64 + ((4 + quad) ^ (n & 7)) * 8);
        }
        if (pf) ISSUE_B1(kc + 2, 1);
        BAR();
        __builtin_amdgcn_s_setprio(1);
#pragma unroll
        for (int mt = 0; mt < 4; ++mt)
#pragma unroll
            for (int nt = 0; nt < 2; ++nt)
                acc[mt][2 + nt] = __builtin_amdgcn_mfma_f32_16x16x32_bf16(af[mt], bfr[nt], acc[mt][2 + nt], 0, 0, 0);
        __builtin_amdgcn_s_setprio(0);
    }

    if (n0 < 1536) {
        const bool isq = (n0 < 768);
        const float sc = isq ? (0.125f * LOG2E) : 1.0f;
#pragma unroll
        for (int nt = 0; nt < 4; ++nt) {
            int n = n0 + wn + nt * 16 + lane15;
            int rem = isq ? n : (n - 768);
            int h = rem >> 6;
            int d = n & 63;
            float bv = bias[n];
            __bf16* dst = isq ? qb : kb;
#pragma unroll
            for (int mt = 0; mt < 4; ++mt) {
#pragma unroll
                for (int reg = 0; reg < 4; ++reg) {
                    int mr = m0 + wm + mt * 16 + quad * 4 + reg;
                    int bb = mr >> 10, t = mr & 1023;
                    dst[(((size_t)bb * H_ + h) * T_ + t) * D_ + d] =
                        (__bf16)((acc[mt][nt][reg] + bv) * sc);
                }
            }
        }
    } else {
        // v block: transpose through LDS; store with within-64-key permutation
        // storage position s (0..63) holds key t_local = (s&3)*16 + (s>>2)
        __syncthreads();   // drain all waves' K-loop LDS reads before reuse
        __bf16* vls = smem;  // [128 n][264]  (33792 elems <= 73728)
#pragma unroll
        for (int nt = 0; nt < 4; ++nt) {
            int nl = wn + nt * 16 + lane15;
            float bv = bias[n0 + nl];
#pragma unroll
            for (int mt = 0; mt < 4; ++mt)
#pragma unroll
                for (int reg = 0; reg < 4; ++reg)
                    vls[nl * 264 + wm + mt * 16 + quad * 4 + reg] =
                        (__bf16)(acc[mt][nt][reg] + bv);
        }
        __syncthreads();
        int nl = tid >> 2;
        int t0 = (tid & 3) * 64;
        int n = n0 + nl;
        int h = (n - 1536) >> 6;
        int d = n & 63;
        int bb = m0 >> 10, tg = (m0 & 1023) + t0;
        __bf16* dst = vbt + (((size_t)bb * H_ + h) * D_ + d) * T_ + tg;
        const __bf16* srcl = vls + nl * 264 + t0;
#pragma unroll
        for (int c = 0; c < 8; ++c) {
            bf16x8 v;
#pragma unroll
            for (int i = 0; i < 8; ++i) {
                int s = c * 8 + i;
                v[i] = srcl[(s & 3) * 16 + (s >> 2)];
            }
            *(bf16x8*)(dst + c * 8) = v;
        }
    }
#undef ISSUE_A2
#undef ISSUE_B1
#undef BAR
}

// ---------------- proj GEMM v5 (round-2 proven): 128M x 64N, BK=64, single-buffer LDS ----------------
__global__ __launch_bounds__(256) void proj_gemm_mfma(const __bf16* __restrict__ A,
                                                      const __bf16* __restrict__ Bt,
                                                      const float* __restrict__ bias,
                                                      float* __restrict__ out) {
    __shared__ __bf16 As[128 * 64];
    __shared__ __bf16 Bs[64 * 64];
    const int tid = threadIdx.x;
    const int wave = tid >> 6, lane = tid & 63;
    const int lane15 = lane & 15, quad = lane >> 4;
    const int bid = blockIdx.x;
    const int m0 = ((bid & 7) * 8 + ((bid >> 3) & 7)) * 128;
    const int n0 = (bid >> 6) * 64;
    const int wm = wave * 32;
    f32x4 acc[2][4] = {};

#define PSTAGE(KC)                                                                  \
    {                                                                               \
        const int k0s = (KC) * 64;                                                  \
        _Pragma("unroll")                                                           \
        for (int r = 0; r < 4; ++r) {                                               \
            int p = r * 256 + tid;                                                  \
            int mrow = p >> 3, csw = p & 7;                                         \
            int ksrc = (csw ^ (mrow & 7)) * 8;                                      \
            __builtin_amdgcn_global_load_lds(                                       \
                (gptr_t)(A + (size_t)(m0 + mrow) * 768 + k0s + ksrc),               \
                (lptr_t)(&As[0] + (r * 256 + wave * 64) * 8), 16, 0, 0);            \
        }                                                                           \
        _Pragma("unroll")                                                           \
        for (int r = 0; r < 2; ++r) {                                               \
            int p = r * 256 + tid;                                                  \
            int nrow = p >> 3, csw = p & 7;                                         \
            int ksrc = (csw ^ (nrow & 7)) * 8;                                      \
            __builtin_amdgcn_global_load_lds(                                       \
                (gptr_t)(Bt + (size_t)(n0 + nrow) * 768 + k0s + ksrc),              \
                (lptr_t)(&Bs[0] + (r * 256 + wave * 64) * 8), 16, 0, 0);            \
        }                                                                           \
    }

    for (int kc = 0; kc < 12; ++kc) {
        PSTAGE(kc);
        __syncthreads();
#pragma unroll
        for (int ks = 0; ks < 2; ++ks) {
            bf16x8 af[2], bf[4];
#pragma unroll
            for (int mt = 0; mt < 2; ++mt) {
                int m = wm + mt * 16 + lane15;
                int csw = (ks * 4 + quad) ^ (m & 7);
                af[mt] = *(const bf16x8*)(&As[0] + m * 64 + csw * 8);
            }
#pragma unroll
            for (int nt = 0; nt < 4; ++nt) {
                int n = nt * 16 + lane15;
                int csw = (ks * 4 + quad) ^ (n & 7);
                bf[nt] = *(const bf16x8*)(&Bs[0] + n * 64 + csw * 8);
            }
#pragma unroll
            for (int mt = 0; mt < 2; ++mt)
#pragma unroll
                for (int nt = 0; nt < 4; ++nt)
                    acc[mt][nt] = __builtin_amdgcn_mfma_f32_16x16x32_bf16(af[mt], bf[nt], acc[mt][nt], 0, 0, 0);
        }
        __syncthreads();
    }

#pragma unroll
    for (int nt = 0; nt < 4; ++nt) {
        int n = n0 + nt * 16 + lane15;
        float bv = bias[n];
#pragma unroll
        for (int mt = 0; mt < 2; ++mt) {
#pragma unroll
            for (int reg = 0; reg < 4; ++reg) {
                int mr = m0 + wm + mt * 16 + quad * 4 + reg;
                out[(size_t)mr * C_ + n] = acc[mt][nt][reg] + bv;
            }
        }
    }
#undef PSTAGE
}

// ---------------- MFMA flash attention v6 (best measured rest-of-pipeline): causal-balanced q-tile pairing ----------------
// 64-row q-tiles (16 total, kunits = qt+1). Each block handles the PAIR (15-y, y):
// kunits sum = 17 for EVERY block -> perfectly balanced grid. Grid (96,8); LDS 41KB
// -> 3 blocks/CU. The global_load_lds double-buffer IS the prefetch pipeline —
// do not remove it (round 10: L2-direct was 5% MfmaUtil, -60%).
__global__ __launch_bounds__(256) void attn_mfma(const __bf16* __restrict__ qb,
                                                 const __bf16* __restrict__ kb,
                                                 const __bf16* __restrict__ vbt,
                                                 __bf16* __restrict__ ao) {
    __shared__ __bf16 Ks[2][64 * 64];
    __shared__ __bf16 Vts[2][64 * 64];
    __shared__ __bf16 Ps[4 * 16 * 72];

    const int tid = threadIdx.x;
    const int wave = tid >> 6, lane = tid & 63;
    const int lane15 = lane & 15, quad = lane >> 4;
    const int bh = blockIdx.x;
    const int y = blockIdx.y;
    const int qtA = 15 - y;            // long segment: 8..15
    const int qtB = y;                 // short segment: 0..7
    const int kuA = qtA + 1;           // 9..16 units
    const int UT = 17;                 // kuA + (qtB+1) == 17 always
    const int b = bh / H_, h = bh % H_;

    const __bf16* Kb = kb + (size_t)bh * T_ * D_;
    const __bf16* Vb = vbt + (size_t)bh * D_ * T_;
    __bf16* Pw = Ps + wave * 16 * 72;

    // Q fragments for both segments (wave owns 16 q-rows per segment)
    bf16x8 qfA[2], qfB[2];
    {
        const __bf16* qrA = qb + ((size_t)bh * T_ + qtA * 64 + wave * 16 + lane15) * D_ + quad * 8;
        qfA[0] = *(const bf16x8*)qrA;
        qfA[1] = *(const bf16x8*)(qrA + 32);
        const __bf16* qrB = qb + ((size_t)bh * T_ + qtB * 64 + wave * 16 + lane15) * D_ + quad * 8;
        qfB[0] = *(const bf16x8*)qrB;
        qfB[1] = *(const bf16x8*)(qrB + 32);
    }

    f32x4 o[4] = {};
    float lsum[4] = {0.f, 0.f, 0.f, 0.f};

#define ASTAGE(K0S, BUF)                                                           \
    {                                                                              \
        const int k0s = (K0S);                                                     \
        _Pragma("unroll")                                                          \
        for (int r = 0; r < 2; ++r) {                                              \
            int p = r * 256 + tid;                                                 \
            int row = p >> 3, c = p & 7;                                           \
            int cs = (c ^ (row & 7)) * 8;                                          \
            __builtin_amdgcn_global_load_lds(                                      \
                (gptr_t)(Kb + (size_t)(k0s + row) * D_ + cs),                      \
                (lptr_t)(&Ks[BUF][0] + (r * 256 + wave * 64) * 8), 16, 0, 0);      \
            __builtin_amdgcn_global_load_lds(                                      \
                (gptr_t)(Vb + (size_t)row * T_ + k0s + cs),                        \
                (lptr_t)(&Vts[BUF][0] + (r * 256 + wave * 64) * 8), 16, 0, 0);     \
        }                                                                          \
    }

    ASTAGE(0, 0);

    for (int u = 0; u < UT; ++u) {
        const int seg = (u >= kuA) ? 1 : 0;
        const int qt = seg ? qtB : qtA;
        const int k0 = (seg ? (u - kuA) : u) * 64;
        __syncthreads();
        if (u + 1 < UT) {
            const int un = u + 1;
            const int k0n = (un < kuA) ? un * 64 : (un - kuA) * 64;
            ASTAGE(k0n, un & 1);
        }
        const __bf16* Kc = &Ks[u & 1][0];
        const __bf16* Vc = &Vts[u & 1][0];

        const bf16x8 q0r = seg ? qfB[0] : qfA[0];
        const bf16x8 q1r = seg ? qfB[1] : qfA[1];

        f32x4 s[4];
        __builtin_amdgcn_s_setprio(1);
#pragma unroll
        for (int kt = 0; kt < 4; ++kt) {
            int row = kt * 16 + lane15;
            bf16x8 kf0 = *(const bf16x8*)(Kc + row * 64 + ((quad) ^ (row & 7)) * 8);
            bf16x8 kf1 = *(const bf16x8*)(Kc + row * 64 + ((4 + quad) ^ (row & 7)) * 8);
            f32x4 t = {};
            t = __builtin_amdgcn_mfma_f32_16x16x32_bf16(q0r, kf0, t, 0, 0, 0);
            t = __builtin_amdgcn_mfma_f32_16x16x32_bf16(q1r, kf1, t, 0, 0, 0);
            s[kt] = t;
        }
        __builtin_amdgcn_s_setprio(0);

        const bool diag = (k0 == qt * 64);
#pragma unroll
        for (int r = 0; r < 4; ++r) {
            bf16x4 pk;
#pragma unroll
            for (int kt = 0; kt < 4; ++kt) {
                int col = k0 + kt * 16 + lane15;
                float p = __builtin_amdgcn_exp2f(s[kt][r]);
                if (diag) {
                    int qrow = qt * 64 + wave * 16 + quad * 4 + r;
                    if (col > qrow) p = 0.f;
                }
                lsum[r] += p;
                pk[kt] = (__bf16)p;
            }
            // storage column = lane15*4 + kt  (matches vbt's permuted key order)
            *(bf16x4*)(Pw + (quad * 4 + r) * 72 + lane15 * 4) = pk;
        }

        bf16x8 vf[4][2];
#pragma unroll
        for (int dt = 0; dt < 4; ++dt) {
            int row = dt * 16 + lane15;
#pragma unroll
            for (int half = 0; half < 2; ++half)
                vf[dt][half] = *(const bf16x8*)(Vc + row * 64 + ((half * 4 + quad) ^ (row & 7)) * 8);
        }
        __builtin_amdgcn_s_setprio(1);
#pragma unroll
        for (int half = 0; half < 2; ++half) {
            bf16x8 pf = *(const bf16x8*)(Pw + lane15 * 72 + half * 32 + quad * 8);
#pragma unroll
            for (int dt = 0; dt < 4; ++dt)
                o[dt] = __builtin_amdgcn_mfma_f32_16x16x32_bf16(pf, vf[dt][half], o[dt], 0, 0, 0);
        }
        __builtin_amdgcn_s_setprio(0);

        // segment finalize (block-uniform condition)
        if (u == kuA - 1 || u == UT - 1) {
            const int q0 = qt * 64;
            float inv[4];
#pragma unroll
            for (int r = 0; r < 4; ++r) {
                float ls = lsum[r];
                ls += __shfl_xor(ls, 1);
                ls += __shfl_xor(ls, 2);
                ls += __shfl_xor(ls, 4);
                ls += __shfl_xor(ls, 8);
                inv[r] = 1.0f / ls;
                lsum[r] = 0.f;
            }
#pragma unroll
            for (int dt = 0; dt < 4; ++dt) {
#pragma unroll
                for (int r = 0; r < 4; ++r) {
                    int t = q0 + wave * 16 + quad * 4 + r;
                    ao[((size_t)(b * T_ + t)) * C_ + h * 64 + dt * 16 + lane15] =
                        (__bf16)(o[dt][r] * inv[r]);
                }
                o[dt] = f32x4{};
            }
        }
    }
#undef ASTAGE
}

extern "C" void kernel_launch(void* const* d_in, const int* in_sizes, int n_in,
                              void* d_out, int out_size, void* d_ws, size_t ws_size,
                              hipStream_t stream) {
    const float* x = (const float*)d_in[0];
    const float* w_attn = (const float*)d_in[1];
    const float* b_attn = (const float*)d_in[2];
    const float* w_proj = (const float*)d_in[3];
    const float* b_proj = (const float*)d_in[4];
    float* out = (float*)d_out;

    __bf16* xb = (__bf16*)d_ws;
    __bf16* wat = xb + (size_t)M_ * C_;
    __bf16* wpt = wat + (size_t)N3C * C_;
    __bf16* qb = wpt + (size_t)C_ * C_;         // pre-scaled by (1/8)log2e
    __bf16* kb = qb + (size_t)96 * T_ * D_;
    __bf16* vbt = kb + (size_t)96 * T_ * D_;    // [96][64][1024], permuted keys
    __bf16* ao = vbt + (size_t)96 * T_ * D_;

    prepass<<<5376, 256, 0, stream>>>(x, xb, w_attn, wat, w_proj, wpt);
    qkv_gemm_mfma<<<576, 512, 0, stream>>>(xb, wat, b_attn, qb, kb, vbt);
    attn_mfma<<<dim3(96, 8), 256, 0, stream>>>(qb, kb, vbt, ao);
    proj_gemm_mfma<<<768, 256, 0, stream>>>(ao, wpt, b_proj, out);
}